// Round 1
// baseline (185.295 us; speedup 1.0000x reference)
//
#include <hip/hip_runtime.h>

#define B 2
#define L 384
#define EMBED 1280
#define HID 256
#define NBINS 10
#define MROWS (B * L)  // 768

// K1: xi = x@Wi+bi  stored row-major [B*L, HID]
//     xjT = (x@Wj+bj) stored transposed per batch: [B][HID][L]
// Grid: (MROWS/16, HID/32) = (48, 8), block 256.
// Thread (nloc = tid&31, mgrp = tid>>5) computes 2 rows x 1 col for both mats.
__global__ __launch_bounds__(256) void k1_proj(
    const float* __restrict__ x, const float* __restrict__ Wi, const float* __restrict__ bi,
    const float* __restrict__ Wj, const float* __restrict__ bj,
    float* __restrict__ xi, float* __restrict__ xjT)
{
    const int tid = threadIdx.x;
    const int nloc = tid & 31;
    const int mgrp = tid >> 5;            // 0..7
    const int n = blockIdx.y * 32 + nloc; // 0..255
    const int m0 = blockIdx.x * 16;
    const int row0 = m0 + mgrp * 2;

    float acci[2] = {0.f, 0.f};
    float accj[2] = {0.f, 0.f};

    for (int k = 0; k < EMBED; k += 4) {
        float4 xv[2];
        xv[0] = *(const float4*)(x + (size_t)row0 * EMBED + k);
        xv[1] = *(const float4*)(x + (size_t)(row0 + 1) * EMBED + k);
#pragma unroll
        for (int kk = 0; kk < 4; ++kk) {
            float wi = Wi[(k + kk) * HID + n];
            float wj = Wj[(k + kk) * HID + n];
#pragma unroll
            for (int r = 0; r < 2; ++r) {
                float xs = (&xv[r].x)[kk];
                acci[r] = fmaf(xs, wi, acci[r]);
                accj[r] = fmaf(xs, wj, accj[r]);
            }
        }
    }

    const float biv = bi[n], bjv = bj[n];
#pragma unroll
    for (int r = 0; r < 2; ++r) {
        const int m = row0 + r;
        const int bb = m / L;
        const int l = m - bb * L;
        xi[(size_t)m * HID + n] = acci[r] + biv;
        xjT[((size_t)bb * HID + n) * L + l] = accj[r] + bjv;
    }
}

// K2: out[b,i,j,:] = relu(xi[b,i,:] * xj[b,j,:]) @ Wo + bo
// Grid: (L/2, B), block 384 (one thread per j; 2 i-rows per block).
// xi[h] and Wo[h,:] are wave-uniform -> scalar loads; xjT load is coalesced.
__global__ __launch_bounds__(384) void k2_pair(
    const float* __restrict__ xi, const float* __restrict__ xjT,
    const float* __restrict__ Wo, const float* __restrict__ bo,
    float* __restrict__ out)
{
    __shared__ float sout[L * NBINS];  // 15360 B
    const int tid = threadIdx.x;       // == j
    const int b = blockIdx.y;
    const int i0 = blockIdx.x * 2;

    const float* xjb = xjT + (size_t)b * HID * L;
    const float* xia = xi + ((size_t)(b * L + i0)) * HID;
    const float* xib = xia + HID;

    float acc0[NBINS], acc1[NBINS];
#pragma unroll
    for (int nn = 0; nn < NBINS; ++nn) { acc0[nn] = 0.f; acc1[nn] = 0.f; }

#pragma unroll 4
    for (int h = 0; h < HID; ++h) {
        const float xjv = xjb[(size_t)h * L + tid];
        const float a = xia[h];
        const float c = xib[h];
        const float p0 = fmaxf(a * xjv, 0.f);
        const float p1 = fmaxf(c * xjv, 0.f);
#pragma unroll
        for (int nn = 0; nn < NBINS; ++nn) {
            const float w = Wo[h * NBINS + nn];
            acc0[nn] = fmaf(p0, w, acc0[nn]);
            acc1[nn] = fmaf(p1, w, acc1[nn]);
        }
    }

    float bov[NBINS];
#pragma unroll
    for (int nn = 0; nn < NBINS; ++nn) bov[nn] = bo[nn];

    // row i0: stage in LDS, store coalesced
#pragma unroll
    for (int nn = 0; nn < NBINS; ++nn) sout[tid * NBINS + nn] = acc0[nn] + bov[nn];
    __syncthreads();
    {
        float* orow = out + ((size_t)(b * L + i0) * L) * NBINS;
        for (int t = tid; t < L * NBINS; t += 384) orow[t] = sout[t];
    }
    __syncthreads();
    // row i0+1
#pragma unroll
    for (int nn = 0; nn < NBINS; ++nn) sout[tid * NBINS + nn] = acc1[nn] + bov[nn];
    __syncthreads();
    {
        float* orow = out + ((size_t)(b * L + i0 + 1) * L) * NBINS;
        for (int t = tid; t < L * NBINS; t += 384) orow[t] = sout[t];
    }
}

extern "C" void kernel_launch(void* const* d_in, const int* in_sizes, int n_in,
                              void* d_out, int out_size, void* d_ws, size_t ws_size,
                              hipStream_t stream)
{
    const float* x  = (const float*)d_in[0];
    const float* Wi = (const float*)d_in[1];
    const float* bi = (const float*)d_in[2];
    const float* Wj = (const float*)d_in[3];
    const float* bj = (const float*)d_in[4];
    const float* Wo = (const float*)d_in[5];
    const float* bo = (const float*)d_in[6];
    float* out = (float*)d_out;

    float* xi  = (float*)d_ws;                 // [768, 256]
    float* xjT = xi + (size_t)MROWS * HID;     // [2, 256, 384]

    k1_proj<<<dim3(MROWS / 16, HID / 32), 256, 0, stream>>>(x, Wi, bi, Wj, bj, xi, xjT);
    k2_pair<<<dim3(L / 2, B), 384, 0, stream>>>(xi, xjT, Wo, bo, out);
}

// Round 2
// 141.590 us; speedup vs baseline: 1.3087x; 1.3087x over previous
//
#include <hip/hip_runtime.h>

#define B 2
#define L 384
#define EMBED 1280
#define HID 256
#define NBINS 10
#define MROWS (B * L)  // 768

// ---------------- K1: projection GEMM  C[768,512] = x[768,1280] @ [Wi|Wj] ----
// xi stored [768,256] row-major; xj stored transposed [B][HID][L] for K2 coalescing.
// 64x64 tiles, 4x4 micro-tile, KB=16, split-K=5, atomicAdd epilogue (ws pre-zeroed).
#define TM 64
#define TN 64
#define KB 16
#define KSPLIT 5
#define KCHUNK (EMBED / KSPLIT)  // 256
#define KSTEPS (KCHUNK / KB)     // 16

__global__ __launch_bounds__(256) void k1_proj(
    const float* __restrict__ x,
    const float* __restrict__ Wi, const float* __restrict__ bi,
    const float* __restrict__ Wj, const float* __restrict__ bj,
    float* __restrict__ xi, float* __restrict__ xjT)
{
    __shared__ float xs[KB][TM + 4];  // stride 68 floats = 272 B (16B-aligned, 2-way banks only)
    __shared__ float ws[KB][TN];

    const int tid = threadIdx.x;
    const int tx = tid & 15;          // col group 0..15 -> 4 cols each
    const int ty = tid >> 4;          // row group 0..15 -> 4 rows each
    const int m0 = blockIdx.x * TM;
    const int ncat = blockIdx.y * TN; // 0..511 across [Wi|Wj]
    const bool isJ = ncat >= HID;
    const float* W = isJ ? Wj : Wi;
    const float* bias = isJ ? bj : bi;
    const int n0 = isJ ? (ncat - HID) : ncat;
    const int k0 = blockIdx.z * KCHUNK;

    // staging loader indices
    const int xr = tid >> 2;          // 0..63 (row)
    const int xk = (tid & 3) * 4;     // 0,4,8,12 (k within KB)
    const int wk = tid >> 4;          // 0..15 (k)
    const int wn = (tid & 15) * 4;    // 0..60 (col)

    const float* xptr = x + (size_t)(m0 + xr) * EMBED + k0 + xk;
    const float* wptr = W + (size_t)(k0 + wk) * HID + n0 + wn;

    float4 xv = *(const float4*)xptr;
    float4 wv = *(const float4*)wptr;

    float acc[4][4];
#pragma unroll
    for (int r = 0; r < 4; ++r)
#pragma unroll
        for (int c = 0; c < 4; ++c) acc[r][c] = 0.f;

    for (int s = 0; s < KSTEPS; ++s) {
        // stage prefetched regs -> LDS (xs transposed to [k][row])
        xs[xk + 0][xr] = xv.x;
        xs[xk + 1][xr] = xv.y;
        xs[xk + 2][xr] = xv.z;
        xs[xk + 3][xr] = xv.w;
        *(float4*)&ws[wk][wn] = wv;
        __syncthreads();

        if (s + 1 < KSTEPS) {  // prefetch next tile; latency overlaps compute below
            xv = *(const float4*)(xptr + (s + 1) * KB);
            wv = *(const float4*)(wptr + (size_t)(s + 1) * KB * HID);
        }

#pragma unroll
        for (int k = 0; k < KB; ++k) {
            float4 a4 = *(const float4*)&xs[k][ty * 4];
            float4 b4 = *(const float4*)&ws[k][tx * 4];
            const float* av = (const float*)&a4;
            const float* bv = (const float*)&b4;
#pragma unroll
            for (int r = 0; r < 4; ++r)
#pragma unroll
                for (int c = 0; c < 4; ++c)
                    acc[r][c] = fmaf(av[r], bv[c], acc[r][c]);
        }
        __syncthreads();
    }

    // epilogue: atomic accumulate (bias added once, by z==0 blocks)
    const bool addB = (blockIdx.z == 0);
#pragma unroll
    for (int c = 0; c < 4; ++c) {
        const int n = n0 + tx * 4 + c;
        const float bv = addB ? bias[n] : 0.f;
#pragma unroll
        for (int r = 0; r < 4; ++r) {
            const int m = m0 + ty * 4 + r;
            const float v = acc[r][c] + bv;
            if (!isJ) {
                atomicAdd(&xi[(size_t)m * HID + n], v);
            } else {
                const int bb = m >= L ? 1 : 0;
                const int l = m - bb * L;
                atomicAdd(&xjT[((size_t)bb * HID + n) * L + l], v);
            }
        }
    }
}

// ---------------- K2: out[b,i,j,:] = relu(xi[b,i,:]*xj[b,j,:]) @ Wo + bo ----
// block 192 thr = 3 waves; wave ig owns i-row m = bx*3+ig (uniform -> s_loads);
// thread owns 3 coalesced j (jt, jt+64, jt+128) x 10 bins = 30 accumulators.
// grid (256, 2) = 512 blocks = 2 blocks/CU.
__global__ __launch_bounds__(192) void k2_pair(
    const float* __restrict__ xi, const float* __restrict__ xjT,
    const float* __restrict__ Wo, const float* __restrict__ bo,
    float* __restrict__ out)
{
    __shared__ float sout[3 * 192 * NBINS];  // 23 KB
    const int tid = threadIdx.x;
    const int jt = tid & 63;
    const int ig = tid >> 6;  // 0..2, wave-uniform
    const int m = __builtin_amdgcn_readfirstlane(blockIdx.x * 3 + ig);
    const int bb = m >= L ? 1 : 0;  // block never straddles batch (3 | 384)
    const int jcol0 = blockIdx.y * 192;

    const float* xrow = xi + (size_t)m * HID;                  // scalar (SMEM) loads
    const float* xjb = xjT + (size_t)bb * HID * L + jcol0 + jt;

    float acc[3][NBINS];
#pragma unroll
    for (int s = 0; s < 3; ++s)
#pragma unroll
        for (int n = 0; n < NBINS; ++n) acc[s][n] = 0.f;

#pragma unroll 4
    for (int h = 0; h < HID; ++h) {
        const float xj0 = xjb[h * L];
        const float xj1 = xjb[h * L + 64];
        const float xj2 = xjb[h * L + 128];
        const float a = xrow[h];
        const float p0 = fmaxf(a * xj0, 0.f);
        const float p1 = fmaxf(a * xj1, 0.f);
        const float p2 = fmaxf(a * xj2, 0.f);
#pragma unroll
        for (int n = 0; n < NBINS; ++n) {
            const float w = Wo[h * NBINS + n];
            acc[0][n] = fmaf(p0, w, acc[0][n]);
            acc[1][n] = fmaf(p1, w, acc[1][n]);
            acc[2][n] = fmaf(p2, w, acc[2][n]);
        }
    }

    float bov[NBINS];
#pragma unroll
    for (int n = 0; n < NBINS; ++n) bov[n] = bo[n];

    // stage rows in LDS, copy out coalesced as float2
#pragma unroll
    for (int s = 0; s < 3; ++s)
#pragma unroll
        for (int n = 0; n < NBINS; ++n)
            sout[(ig * 192 + jt + 64 * s) * NBINS + n] = acc[s][n] + bov[n];
    __syncthreads();

    const float2* s2 = (const float2*)sout;
#pragma unroll
    for (int r = 0; r < 3; ++r) {
        float2* dst = (float2*)(out + ((size_t)(blockIdx.x * 3 + r) * L + jcol0) * NBINS);
#pragma unroll
        for (int q = 0; q < 5; ++q)
            dst[q * 192 + tid] = s2[r * 960 + q * 192 + tid];
    }
}

extern "C" void kernel_launch(void* const* d_in, const int* in_sizes, int n_in,
                              void* d_out, int out_size, void* d_ws, size_t ws_size,
                              hipStream_t stream)
{
    const float* x  = (const float*)d_in[0];
    const float* Wi = (const float*)d_in[1];
    const float* bi = (const float*)d_in[2];
    const float* Wj = (const float*)d_in[3];
    const float* bj = (const float*)d_in[4];
    const float* Wo = (const float*)d_in[5];
    const float* bo = (const float*)d_in[6];
    float* out = (float*)d_out;

    float* xi  = (float*)d_ws;                 // [768, 256]
    float* xjT = xi + (size_t)MROWS * HID;     // [2, 256, 384]

    hipMemsetAsync(d_ws, 0, (size_t)MROWS * HID * 2 * sizeof(float), stream);
    k1_proj<<<dim3(MROWS / TM, 512 / TN, KSPLIT), 256, 0, stream>>>(x, Wi, bi, Wj, bj, xi, xjT);
    k2_pair<<<dim3(MROWS / 3, 2), 192, 0, stream>>>(xi, xjT, Wo, bo, out);
}

// Round 3
// 113.446 us; speedup vs baseline: 1.6333x; 1.2481x over previous
//
#include <hip/hip_runtime.h>

#define LSEQ 384
#define EMBED 1280
#define HID 256
#define NBINS 10
#define GM 768          // B*L rows
#define KP 512          // packed K: 2 signs x HID

typedef __attribute__((ext_vector_type(8))) short short8;
typedef __attribute__((ext_vector_type(4))) short short4v;
typedef __attribute__((ext_vector_type(4))) float float4v;
typedef __attribute__((ext_vector_type(2))) float float2v;

__device__ __forceinline__ short f2bf(float f) {
    unsigned u = __builtin_bit_cast(unsigned, f);
    u = (u + 0x7fffu + ((u >> 16) & 1u)) >> 16;   // RNE
    return (short)u;
}

__device__ __forceinline__ void load16_to_lds(const void* g, void* l) {
    __builtin_amdgcn_global_load_lds(
        (const __attribute__((address_space(1))) unsigned int*)g,
        (__attribute__((address_space(3))) unsigned int*)l, 16, 0, 0);
}

// ---------------- K1: C[768,512] = bf16(x) @ bf16([Wi|Wj]) + bias, then pack:
//   n<256 (xi):  Aef[n10][m][h]     = bf16(relu(v)*Wo[h,n])
//                Aef[n10][m][256+h] = bf16(relu(-v)*Wo[h,n])
//   n>=256 (xj): Bef[m][h] = bf16(relu(v)); Bef[m][256+h] = bf16(relu(-v))
// grid (24,16), block 256 (4 waves, each a 16x16 quadrant of a 32x32 C-tile).
__global__ __launch_bounds__(256) void k1_proj_pack(
    const float* __restrict__ x, const float* __restrict__ Wi, const float* __restrict__ bi,
    const float* __restrict__ Wj, const float* __restrict__ bj, const float* __restrict__ Wo,
    short* __restrict__ Aef, short* __restrict__ Bef)
{
    __shared__ short xs[32][32];   // [m][k] bf16
    __shared__ short wn[32][32];   // [n][k] bf16 (W^T tile)

    const int tid = threadIdx.x;
    const int m0 = blockIdx.x * 32;
    const int n0 = blockIdx.y * 32;
    const bool isI = (n0 < HID);
    const float* __restrict__ W = isI ? Wi : Wj;
    const int nc0 = n0 & (HID - 1);

    const int lane = tid & 63;
    const int w = tid >> 6;
    const int mh = w >> 1, nh = w & 1;
    const int l15 = lane & 15, q = lane >> 4;

    const int srow = tid >> 3;          // 0..31
    const int sq = (tid & 7) * 4;       // 0..28

    const float* xp = x + (size_t)(m0 + srow) * EMBED + sq;        // row srow, k sq
    const float* wp = W + (size_t)srow * HID + nc0 + sq;           // k srow, n sq

    float4v acc = {0.f, 0.f, 0.f, 0.f};

    for (int ks = 0; ks < EMBED / 32; ++ks) {
        const float4v xv = *(const float4v*)(xp + ks * 32);
        const float4v wv = *(const float4v*)(wp + (size_t)ks * 32 * HID);
        __syncthreads();   // previous iteration's frag reads complete
        short4v x4;
        x4.x = f2bf(xv.x); x4.y = f2bf(xv.y); x4.z = f2bf(xv.z); x4.w = f2bf(xv.w);
        *(short4v*)&xs[srow][sq] = x4;
        wn[sq + 0][srow] = f2bf(wv.x);
        wn[sq + 1][srow] = f2bf(wv.y);
        wn[sq + 2][srow] = f2bf(wv.z);
        wn[sq + 3][srow] = f2bf(wv.w);
        __syncthreads();
        const short8 a = *(const short8*)&xs[mh * 16 + l15][q * 8];
        const short8 bfr = *(const short8*)&wn[nh * 16 + l15][q * 8];
        acc = __builtin_amdgcn_mfma_f32_16x16x32_bf16(a, bfr, acc, 0, 0, 0);
    }

    const int ncol = n0 + nh * 16 + l15;
    const int mrow0 = m0 + mh * 16;
    if (isI) {
        const int h = ncol;
        float wo[NBINS];
        const float2v* wop = (const float2v*)(Wo + h * NBINS);
#pragma unroll
        for (int c = 0; c < 5; ++c) { float2v t = wop[c]; wo[2 * c] = t.x; wo[2 * c + 1] = t.y; }
        const float bv = bi[h];
#pragma unroll
        for (int r = 0; r < 4; ++r) {
            const int m = mrow0 + q * 4 + r;
            const float v = acc[r] + bv;
            const float p = fmaxf(v, 0.f), pm = fmaxf(-v, 0.f);
            short* ap = Aef + (size_t)m * KP + h;
#pragma unroll
            for (int n = 0; n < NBINS; ++n) {
                ap[(size_t)n * GM * KP]       = f2bf(p  * wo[n]);
                ap[(size_t)n * GM * KP + HID] = f2bf(pm * wo[n]);
            }
        }
    } else {
        const int h = ncol - HID;
        const float bv = bj[h];
#pragma unroll
        for (int r = 0; r < 4; ++r) {
            const int m = mrow0 + q * 4 + r;
            const float v = acc[r] + bv;
            Bef[(size_t)m * KP + h]       = f2bf(fmaxf(v, 0.f));
            Bef[(size_t)m * KP + HID + h] = f2bf(fmaxf(-v, 0.f));
        }
    }
}

// ---------------- K2: out[b,i,j,:] via pair GEMM, K=512, MFMA 16x16x32 ----
// grid (12,12,2), block 256 = 4 waves; block tile i32 x j32 x 10 bins.
// wave w -> quadrant (ih=w>>1, jh=w&1); acc[n] = C 16x16 frag per bin.
__global__ __launch_bounds__(256) void k2_pair_mfma(
    const short* __restrict__ Aef, const short* __restrict__ Bef,
    const float* __restrict__ bo, float* __restrict__ out)
{
    __shared__ __align__(16) char smem[40960];   // K-loop: As 20KB + Bs 2KB; epilogue: sout 40KB
    short* As = (short*)smem;                    // [10][32 rows][32 k]
    short* Bs = (short*)(smem + 20480);          // [32][32]
    float* sout = (float*)smem;                  // [32 i][32 j][10 n]

    const int tid = threadIdx.x;
    const int lane = tid & 63;
    const int w = tid >> 6;
    const int ih = w >> 1, jh = w & 1;
    const int l15 = lane & 15, q = lane >> 4;
    const int b = blockIdx.z;
    const int i0 = blockIdx.x * 32, j0 = blockIdx.y * 32;

    const size_t arow0 = (size_t)(b * LSEQ + i0);
    const size_t brow0 = (size_t)(b * LSEQ + j0);
    const int srow = lane >> 2;          // 0..15
    const int skb = (lane & 3) * 8;      // shorts (16B steps)

    float4v acc[NBINS];
#pragma unroll
    for (int n = 0; n < NBINS; ++n) acc[n] = (float4v){0.f, 0.f, 0.f, 0.f};

    for (int ks = 0; ks < KP / 32; ++ks) {
        const int k0 = ks * 32;
        __syncthreads();
        // wave w stages A planes w, w+4; then w<2: plane 8+w, else B half (w-2)
        {
            const int p1 = w, p2 = w + 4;
#pragma unroll
            for (int hh = 0; hh < 2; ++hh) {
                load16_to_lds(Aef + ((size_t)p1 * GM + arow0 + hh * 16 + srow) * KP + k0 + skb,
                              As + p1 * 1024 + hh * 512);
                load16_to_lds(Aef + ((size_t)p2 * GM + arow0 + hh * 16 + srow) * KP + k0 + skb,
                              As + p2 * 1024 + hh * 512);
            }
            if (w < 2) {
                const int p3 = 8 + w;
#pragma unroll
                for (int hh = 0; hh < 2; ++hh)
                    load16_to_lds(Aef + ((size_t)p3 * GM + arow0 + hh * 16 + srow) * KP + k0 + skb,
                                  As + p3 * 1024 + hh * 512);
            } else {
                const int hh = w - 2;
                load16_to_lds(Bef + (brow0 + hh * 16 + srow) * KP + k0 + skb,
                              Bs + hh * 512);
            }
        }
        __syncthreads();
        const short8 bfr = *(const short8*)(Bs + (jh * 16 + l15) * 32 + q * 8);
#pragma unroll
        for (int n = 0; n < NBINS; ++n) {
            const short8 afr = *(const short8*)(As + n * 1024 + (ih * 16 + l15) * 32 + q * 8);
            acc[n] = __builtin_amdgcn_mfma_f32_16x16x32_bf16(afr, bfr, acc[n], 0, 0, 0);
        }
    }
    __syncthreads();   // all frag reads done before sout overwrite

    float bov[NBINS];
    const float2v* bop = (const float2v*)bo;
#pragma unroll
    for (int c = 0; c < 5; ++c) { float2v t = bop[c]; bov[2 * c] = t.x; bov[2 * c + 1] = t.y; }

#pragma unroll
    for (int n = 0; n < NBINS; ++n)
#pragma unroll
        for (int r = 0; r < 4; ++r)
            sout[((ih * 16 + q * 4 + r) * 32 + (jh * 16 + l15)) * NBINS + n] = acc[n][r] + bov[n];
    __syncthreads();

    // coalesced copy: 32 rows x 320 floats = 5120 float2, 20 per thread
    const float2v* s2 = (const float2v*)sout;
#pragma unroll
    for (int t = 0; t < 20; ++t) {
        const int f = t * 256 + tid;
        const int row = f / 160;
        const int rq = f - row * 160;
        float2v* dst = (float2v*)(out + ((size_t)(b * LSEQ + i0 + row) * LSEQ + j0) * NBINS);
        dst[rq] = s2[f];
    }
}

extern "C" void kernel_launch(void* const* d_in, const int* in_sizes, int n_in,
                              void* d_out, int out_size, void* d_ws, size_t ws_size,
                              hipStream_t stream)
{
    const float* x  = (const float*)d_in[0];
    const float* Wi = (const float*)d_in[1];
    const float* bi = (const float*)d_in[2];
    const float* Wj = (const float*)d_in[3];
    const float* bj = (const float*)d_in[4];
    const float* Wo = (const float*)d_in[5];
    const float* bo = (const float*)d_in[6];
    float* out = (float*)d_out;

    short* Aef = (short*)d_ws;                       // [10][768][512] bf16 = 7.86 MB
    short* Bef = Aef + (size_t)NBINS * GM * KP;      // [768][512]     bf16 = 0.79 MB

    k1_proj_pack<<<dim3(GM / 32, KP / 32), 256, 0, stream>>>(x, Wi, bi, Wj, bj, Wo, Aef, Bef);
    k2_pair_mfma<<<dim3(LSEQ / 32, LSEQ / 32, 2), 256, 0, stream>>>(Aef, Bef, bo, out);
}

// Round 4
// 107.506 us; speedup vs baseline: 1.7236x; 1.0553x over previous
//
#include <hip/hip_runtime.h>

#define LSEQ 384
#define EMBED 1280
#define HID 256
#define NBINS 10
#define GM 768          // B*L rows
#define KP 512          // packed K: 2 signs x HID

typedef __attribute__((ext_vector_type(8))) short short8;
typedef __attribute__((ext_vector_type(4))) short short4v;
typedef __attribute__((ext_vector_type(4))) float float4v;
typedef __attribute__((ext_vector_type(2))) float float2v;

__device__ __forceinline__ unsigned bfbits(float f) {
    unsigned u = __builtin_bit_cast(unsigned, f);
    return (u + 0x7fffu + ((u >> 16) & 1u)) >> 16;   // RNE
}
__device__ __forceinline__ short f2bf(float f) { return (short)bfbits(f); }

__device__ __forceinline__ void load16_to_lds(const void* g, void* l) {
    __builtin_amdgcn_global_load_lds(
        (const __attribute__((address_space(1))) unsigned int*)g,
        (__attribute__((address_space(3))) unsigned int*)l, 16, 0, 0);
}

// ---------------- P: xb = bf16(x) [768][1280]; WT = bf16([Wi|Wj]^T) [512][1280]
// blocks 0..479: x convert (8 elems/thread, fully coalesced)
// blocks 480..1119: 32x32 LDS tile transpose of Wi/Wj (conflict-free, padded)
__global__ __launch_bounds__(256) void k_prep(
    const float* __restrict__ x, const float* __restrict__ Wi, const float* __restrict__ Wj,
    short* __restrict__ xb, short* __restrict__ WT)
{
    __shared__ float tile[32][33];
    const int t = threadIdx.x;
    int bx = blockIdx.x;
    if (bx < 480) {
        const int idx = bx * 256 + t;
        const float4v a = ((const float4v*)x)[idx * 2];
        const float4v b = ((const float4v*)x)[idx * 2 + 1];
        short8 o;
        o[0] = f2bf(a.x); o[1] = f2bf(a.y); o[2] = f2bf(a.z); o[3] = f2bf(a.w);
        o[4] = f2bf(b.x); o[5] = f2bf(b.y); o[6] = f2bf(b.z); o[7] = f2bf(b.w);
        ((short8*)xb)[idx] = o;
    } else {
        bx -= 480;
        const int isJ = bx >= 320 ? 1 : 0;
        if (isJ) bx -= 320;
        const int tk = bx % 40, tn = bx / 40;
        const int k0 = tk * 32, n0 = tn * 32;
        const float* __restrict__ W = isJ ? Wj : Wi;
        const int r = t >> 3, c4 = (t & 7) * 4;
        const float4v v = *(const float4v*)(W + (size_t)(k0 + r) * HID + n0 + c4);
        tile[r][c4 + 0] = v.x; tile[r][c4 + 1] = v.y;
        tile[r][c4 + 2] = v.z; tile[r][c4 + 3] = v.w;
        __syncthreads();
        const int n = r, kc = c4;   // reuse decomposition for transposed write
        short4v o;
        o.x = f2bf(tile[kc + 0][n]); o.y = f2bf(tile[kc + 1][n]);
        o.z = f2bf(tile[kc + 2][n]); o.w = f2bf(tile[kc + 3][n]);
        *(short4v*)(WT + (size_t)(isJ * HID + n0 + n) * EMBED + k0 + kc) = o;
    }
}

// ---------------- G: C[768,512] = xb @ WT^T (bf16 MFMA, fp32 out, no bias)
// tile 32x32, KB=64, double-buffered global_load_lds; grid (24,16)=384 blocks.
// wave w = quadrant (mh=w&1, nh=w>>1); 2 MFMAs + 2 staging loads per wave per ks.
__global__ __launch_bounds__(256) void k_gemm(
    const short* __restrict__ xb, const short* __restrict__ WT, float* __restrict__ C)
{
    __shared__ short As[2][32 * 64];
    __shared__ short Bs[2][32 * 64];
    const int tid = threadIdx.x;
    const int lane = tid & 63, w = tid >> 6;
    const int mh = w & 1, nh = w >> 1;
    const int l15 = lane & 15, q = lane >> 4;
    const int m0 = blockIdx.x * 32, n0 = blockIdx.y * 32;
    const int lrow = lane >> 3, lcol = (lane & 7) * 8;   // 8 rows x 128B per wave-load

    const short* agp = xb + (size_t)(m0 + 8 * w + lrow) * EMBED + lcol;
    const short* bgp = WT + (size_t)(n0 + 8 * w + lrow) * EMBED + lcol;

    float4v acc = {0.f, 0.f, 0.f, 0.f};

    // prologue stage ks=0 -> buf0
    load16_to_lds(agp, &As[0][w * 512]);
    load16_to_lds(bgp, &Bs[0][w * 512]);
    __syncthreads();

    for (int ks = 0; ks < 20; ++ks) {
        const int cur = ks & 1;
        if (ks < 19) {
            load16_to_lds(agp + (ks + 1) * 64, &As[1 - cur][w * 512]);
            load16_to_lds(bgp + (ks + 1) * 64, &Bs[1 - cur][w * 512]);
        }
#pragma unroll
        for (int kk = 0; kk < 2; ++kk) {
            const short8 af = *(const short8*)&As[cur][(mh * 16 + l15) * 64 + kk * 32 + q * 8];
            const short8 bf = *(const short8*)&Bs[cur][(nh * 16 + l15) * 64 + kk * 32 + q * 8];
            acc = __builtin_amdgcn_mfma_f32_16x16x32_bf16(af, bf, acc, 0, 0, 0);
        }
        __syncthreads();
    }

#pragma unroll
    for (int r = 0; r < 4; ++r)
        C[(size_t)(m0 + mh * 16 + q * 4 + r) * KP + n0 + nh * 16 + l15] = acc[r];
}

// ---------------- K: pack C -> Aef [10][768][512] bf16, Bef [768][512] bf16
// one block per m-row; every global store is a contiguous 1KB dword run.
__global__ __launch_bounds__(256) void k_pack(
    const float* __restrict__ C, const float* __restrict__ Wo,
    const float* __restrict__ bi, const float* __restrict__ bj,
    short* __restrict__ Aef, short* __restrict__ Bef)
{
    __shared__ float xrow[HID];
    __shared__ float woL[NBINS * HID];   // [n][h]
    const int t = threadIdx.x, m = blockIdx.x;

    xrow[t] = C[(size_t)m * KP + t] + bi[t];
#pragma unroll
    for (int c = 0; c < NBINS; ++c) woL[c * HID + t] = Wo[(size_t)t * NBINS + c];

    const float vj = C[(size_t)m * KP + HID + t] + bj[t];
    Bef[(size_t)m * KP + t]       = f2bf(fmaxf(vj, 0.f));
    Bef[(size_t)m * KP + HID + t] = f2bf(fmaxf(-vj, 0.f));
    __syncthreads();

    const int k = 2 * t;
    const int h = k & (HID - 1);
    float v0, v1;
    if (t < 128) { v0 = fmaxf(xrow[h], 0.f);  v1 = fmaxf(xrow[h + 1], 0.f); }
    else         { v0 = fmaxf(-xrow[h], 0.f); v1 = fmaxf(-xrow[h + 1], 0.f); }

#pragma unroll
    for (int n = 0; n < NBINS; ++n) {
        const unsigned lo = bfbits(v0 * woL[n * HID + h]);
        const unsigned hi = bfbits(v1 * woL[n * HID + h + 1]);
        ((unsigned*)(Aef + ((size_t)n * GM + m) * KP))[t] = (hi << 16) | lo;
    }
}

// ---------------- K2: out[b,i,j,:] pair GEMM, K=512, double-buffered.
// grid (12,12,2), block 256 = 4 waves; wave = (ih=w&1, bins (w>>1)*5..+5, BOTH jh).
// Per wave-ks: 5 A-frag + 2 B-frag ds_reads, 10 MFMAs (0.7 reads/MFMA).
__global__ __launch_bounds__(256) void k2_pair(
    const short* __restrict__ Aef, const short* __restrict__ Bef,
    const float* __restrict__ bo, float* __restrict__ out)
{
    __shared__ __align__(16) char smem[45056];
    short* As = (short*)smem;                    // [2][10][1024]
    short* Bs = (short*)(smem + 40960);          // [2][1024]
    float* sout = (float*)smem;                  // [32 i][32 j][10 n] (epilogue)

    const int tid = threadIdx.x;
    const int lane = tid & 63, w = tid >> 6;
    const int ih = w & 1, nb = (w >> 1) * 5;
    const int l15 = lane & 15, q = lane >> 4;
    const int b = blockIdx.z;
    const int i0 = blockIdx.x * 32, j0 = blockIdx.y * 32;

    const size_t arow0 = (size_t)(b * LSEQ + i0);
    const size_t brow0 = (size_t)(b * LSEQ + j0);
    const int srow = lane >> 2;          // 0..15
    const int skb = (lane & 3) * 8;      // shorts (16B steps)

    float4v acc[2][5];
#pragma unroll
    for (int jh = 0; jh < 2; ++jh)
#pragma unroll
        for (int nn = 0; nn < 5; ++nn) acc[jh][nn] = (float4v){0.f, 0.f, 0.f, 0.f};

#define STAGE_K2(ks, buf)                                                               \
    {                                                                                   \
        const int k0_ = (ks) * 32;                                                      \
        short* AsB = As + (buf) * 10240;                                                \
        short* BsB = Bs + (buf) * 1024;                                                 \
        const int p1 = w, p2 = w + 4;                                                   \
        _Pragma("unroll")                                                               \
        for (int hh = 0; hh < 2; ++hh) {                                                \
            load16_to_lds(Aef + ((size_t)p1 * GM + arow0 + hh * 16 + srow) * KP + k0_ + skb, \
                          AsB + p1 * 1024 + hh * 512);                                  \
            load16_to_lds(Aef + ((size_t)p2 * GM + arow0 + hh * 16 + srow) * KP + k0_ + skb, \
                          AsB + p2 * 1024 + hh * 512);                                  \
        }                                                                               \
        if (w < 2) {                                                                    \
            const int p3 = 8 + w;                                                       \
            _Pragma("unroll")                                                           \
            for (int hh = 0; hh < 2; ++hh)                                              \
                load16_to_lds(Aef + ((size_t)p3 * GM + arow0 + hh * 16 + srow) * KP + k0_ + skb, \
                              AsB + p3 * 1024 + hh * 512);                              \
        } else {                                                                        \
            load16_to_lds(Bef + (brow0 + (w - 2) * 16 + srow) * KP + k0_ + skb,         \
                          BsB + (w - 2) * 512);                                         \
        }                                                                               \
    }

    STAGE_K2(0, 0)
    __syncthreads();

    for (int ks = 0; ks < 16; ++ks) {
        const int cur = ks & 1;
        if (ks < 15) STAGE_K2(ks + 1, 1 - cur)
        const short* AsB = As + cur * 10240;
        const short* BsB = Bs + cur * 1024;
        const short8 bfr0 = *(const short8*)(BsB + (0 * 16 + l15) * 32 + q * 8);
        const short8 bfr1 = *(const short8*)(BsB + (1 * 16 + l15) * 32 + q * 8);
#pragma unroll
        for (int nn = 0; nn < 5; ++nn) {
            const short8 afr = *(const short8*)(AsB + (nb + nn) * 1024 + (ih * 16 + l15) * 32 + q * 8);
            acc[0][nn] = __builtin_amdgcn_mfma_f32_16x16x32_bf16(afr, bfr0, acc[0][nn], 0, 0, 0);
            acc[1][nn] = __builtin_amdgcn_mfma_f32_16x16x32_bf16(afr, bfr1, acc[1][nn], 0, 0, 0);
        }
        __syncthreads();
    }

    float bov[NBINS];
    const float2v* bop = (const float2v*)bo;
#pragma unroll
    for (int c = 0; c < 5; ++c) { float2v tv = bop[c]; bov[2 * c] = tv.x; bov[2 * c + 1] = tv.y; }

#pragma unroll
    for (int jh = 0; jh < 2; ++jh)
#pragma unroll
        for (int nn = 0; nn < 5; ++nn)
#pragma unroll
            for (int r = 0; r < 4; ++r)
                sout[((ih * 16 + q * 4 + r) * 32 + (jh * 16 + l15)) * NBINS + nb + nn] =
                    acc[jh][nn][r] + bov[nb + nn];
    __syncthreads();

    // coalesced copy: 32 rows x 320 floats = 5120 float2, 20 per thread
    const float2v* s2 = (const float2v*)sout;
#pragma unroll
    for (int t = 0; t < 20; ++t) {
        const int f = t * 256 + tid;
        const int row = f / 160;
        const int rq = f - row * 160;
        float2v* dst = (float2v*)(out + ((size_t)(b * LSEQ + i0 + row) * LSEQ + j0) * NBINS);
        dst[rq] = s2[f];
    }
}

extern "C" void kernel_launch(void* const* d_in, const int* in_sizes, int n_in,
                              void* d_out, int out_size, void* d_ws, size_t ws_size,
                              hipStream_t stream)
{
    const float* x  = (const float*)d_in[0];
    const float* Wi = (const float*)d_in[1];
    const float* bi = (const float*)d_in[2];
    const float* Wj = (const float*)d_in[3];
    const float* bj = (const float*)d_in[4];
    const float* Wo = (const float*)d_in[5];
    const float* bo = (const float*)d_in[6];
    float* out = (float*)d_out;

    char* p = (char*)d_ws;
    float* C   = (float*)p;                 p += (size_t)GM * KP * 4;        // 1.57 MB
    short* xb  = (short*)p;                 p += (size_t)GM * EMBED * 2;     // 1.97 MB
    short* WT  = (short*)p;                 p += (size_t)KP * EMBED * 2;     // 1.31 MB
    short* Aef = (short*)p;                 p += (size_t)NBINS * GM * KP * 2;// 7.86 MB
    short* Bef = (short*)p;                                                  // 0.79 MB

    k_prep<<<1120, 256, 0, stream>>>(x, Wi, Wj, xb, WT);
    k_gemm<<<dim3(GM / 32, KP / 32), 256, 0, stream>>>(xb, WT, C);
    k_pack<<<GM, 256, 0, stream>>>(C, Wo, bi, bj, Aef, Bef);
    k2_pair<<<dim3(LSEQ / 32, LSEQ / 32, 2), 256, 0, stream>>>(Aef, Bef, bo, out);
}